// Round 5
// baseline (305.636 us; speedup 1.0000x reference)
//
#include <hip/hip_runtime.h>
#include <hip/hip_bf16.h>

#define BB  64
#define JJ  2048
#define DI  16
#define KC  32
#define DOO 32
#define NKO 1024   // KC*DOO

typedef __bf16 bf16;
typedef __attribute__((ext_vector_type(8))) __bf16 bf16x8;
typedef __attribute__((ext_vector_type(4))) __bf16 bf16x4;
typedef __attribute__((ext_vector_type(4))) float f32x4;

// ---------------- prep: W f32 [J][K][Di][Do] -> bf16 MFMA B-fragment layout ----------------
// Coalesced float4 reads -> LDS (pad-33 transpose) -> packed bf16x8 fragment stores.
// Layout (unchanged): Wfrag elem = j*16384 + t*256 + h2*128 + col*8 + e,
//   holding W[j][ko>>5][i=h2*8+e][ko&31] with ko = t*16 + col.
__global__ __launch_bounds__(256)
void prep_w2(const float* __restrict__ W, bf16* __restrict__ Wfrag)
{
    __shared__ float wl[8 * 528];   // 8 k-loc x (16 i x 33 pad)
    const int tid = threadIdx.x;
    const int j = blockIdx.x;
    const float* Wj = W + (size_t)j * 16384;
    bf16* Fj = Wfrag + (size_t)j * 16384;

    for (int kg = 0; kg < 4; ++kg) {
        // read 4096 f32 (8 capsules) fully coalesced
#pragma unroll
        for (int it = 0; it < 4; ++it) {
            int q = it * 256 + tid;                 // float4 index < 1024
            float4 v4 = *reinterpret_cast<const float4*>(Wj + (size_t)kg * 4096 + (size_t)q * 4);
            int flat = q * 4;
            int kl = flat >> 9, rem = flat & 511;
            int i = rem >> 5, o = rem & 31;
            float* d = wl + kl * 528 + i * 33 + o;
            d[0] = v4.x; d[1] = v4.y; d[2] = v4.z; d[3] = v4.w;
        }
        __syncthreads();
        // write 512 16B fragment chunks (8 kl x 2 p x 2 h2 x 16 col)
#pragma unroll
        for (int it = 0; it < 2; ++it) {
            int q = it * 256 + tid;                 // chunk < 512
            int col = q & 15, h2 = (q >> 4) & 1, p = (q >> 5) & 1, kl = q >> 6;
            int t = (kg * 8 + kl) * 2 + p;
            int o = p * 16 + col;
            bf16x8 o8;
#pragma unroll
            for (int e = 0; e < 8; ++e)
                o8[e] = (bf16)wl[kl * 528 + (h2 * 8 + e) * 33 + o];
            *reinterpret_cast<bf16x8*>(Fj + t * 256 + h2 * 128 + col * 8) = o8;
        }
        __syncthreads();
    }
}

// ---------------- prep: X f32 [B][J][Di] -> bf16 MFMA A-fragment layout ----------------
// Xfrag[((j*4 + c)*32 + l)*8 + e] = X[b = c*16 + (l&15)][j][i = (l>>4)*8 + e]
__global__ __launch_bounds__(256)
void prep_x(const float* __restrict__ X, bf16* __restrict__ Xfrag)
{
    int flat = blockIdx.x * 256 + threadIdx.x;        // < 2048*4*32 = 262144
    int l = flat & 31;
    int c = (flat >> 5) & 3;
    int j = flat >> 7;
    int b = c * 16 + (l & 15);
    int i0 = (l >> 4) * 8;
    const float* src = X + ((size_t)b * JJ + j) * DI + i0;
    bf16x8 o8;
#pragma unroll
    for (int e = 0; e < 8; ++e) o8[e] = (bf16)src[e];
    *reinterpret_cast<bf16x8*>(Xfrag + (size_t)flat * 8) = o8;
}

// XCD-aware block decode: ids with the same (id&7) land on the same XCD (round-robin).
// jr = (id>>5)*8 + (id&7), chunk = (id>>3)&3  -> the 4 chunk-blocks of one j-range
// share an XCD and thus L2-share their Wfrag slice. Requires P % 8 == 0.
__device__ __forceinline__ void decode_blk(int id, int useXcd, int& c, int& jr)
{
    if (useXcd) { c = (id >> 3) & 3; jr = ((id >> 5) << 3) | (id & 7); }
    else        { c = id & 3;        jr = id >> 2; }
}

// ---------------- routing iteration 0 (uniform c=1/32): pure MFMA stream ----------------
template<int UF>
__global__ __launch_bounds__(1024, 8)
void caps_init(const bf16* __restrict__ Xfrag, const bf16* __restrict__ Wfrag,
               const float* __restrict__ Xf, const float* __restrict__ Wf,
               bf16* __restrict__ partial, int Jc)
{
    const int tid  = threadIdx.x;
    const int w    = tid >> 6;
    const int lane = tid & 63;
    const int l5   = lane & 31;
    const bool hi  = lane >= 32;
    int c, jr; decode_blk(blockIdx.x, UF, c, jr);

    const f32x4 ZV = {};
    const bf16x8 ZB = {};
    f32x4 acc[4] = {ZV, ZV, ZV, ZV};

    const int j0 = jr * Jc;
    int jend = j0 + Jc; if (jend > JJ) jend = JJ;

    int j = j0;
    if constexpr (UF) {
        for (; j + 1 < jend; j += 2) {            // lanes>=32 carry j+1 (K rows 16..31)
            const int js = j + (hi ? 1 : 0);
            bf16x8 afr = *reinterpret_cast<const bf16x8*>(
                Xfrag + (((size_t)js * 4 + c) * 32 + l5) * 8);
#pragma unroll
            for (int t2 = 0; t2 < 4; ++t2) {
                bf16x8 bfr = *reinterpret_cast<const bf16x8*>(
                    Wfrag + (((size_t)js * 64 + w * 4 + t2) * 32 + l5) * 8);
                acc[t2] = __builtin_amdgcn_mfma_f32_16x16x32_bf16(afr, bfr, acc[t2], 0, 0, 0);
            }
        }
    }
    for (; j < jend; ++j) {    // tail / raw-f32 fallback
        bf16x8 afr = ZB;
        if (!hi) {
            if constexpr (UF) {
                afr = *reinterpret_cast<const bf16x8*>(Xfrag + (((size_t)j * 4 + c) * 32 + l5) * 8);
            } else {
                const float* s = Xf + ((size_t)(c * 16 + (l5 & 15)) * JJ + j) * DI + (l5 >> 4) * 8;
#pragma unroll
                for (int e = 0; e < 8; ++e) afr[e] = (bf16)s[e];
            }
        }
#pragma unroll
        for (int t2 = 0; t2 < 4; ++t2) {
            bf16x8 bfr = ZB;
            if (!hi) {
                if constexpr (UF) {
                    bfr = *reinterpret_cast<const bf16x8*>(
                        Wfrag + (((size_t)j * 64 + w * 4 + t2) * 32 + l5) * 8);
                } else {
                    int ko = (w * 4 + t2) * 16 + (l5 & 15);
                    const float* s = Wf + (size_t)j * 16384 + (size_t)(ko >> 5) * 512
                                   + (size_t)((l5 >> 4) * 8) * 32 + (ko & 31);
#pragma unroll
                    for (int e = 0; e < 8; ++e) bfr[e] = (bf16)s[e * 32];
                }
            }
            acc[t2] = __builtin_amdgcn_mfma_f32_16x16x32_bf16(afr, bfr, acc[t2], 0, 0, 0);
        }
    }

    bf16* pout = partial + (size_t)jr * (BB * NKO);
#pragma unroll
    for (int t2 = 0; t2 < 4; ++t2) {
        bf16x4 o4;
#pragma unroll
        for (int r = 0; r < 4; ++r) o4[r] = (bf16)(acc[t2][r] * 0.03125f);
        *reinterpret_cast<bf16x4*>(pout + (((size_t)c * 64 + (w * 4 + t2)) * 64 + lane) * 4) = o4;
    }
}

// ---------------- routing iteration 1/2: 2-j batched logits -> softmax -> accumulate ----------------
// vsum hoisted to 16 regs (j-invariant). hat[2][4] held across phases -> phase C pure VALU.
// 2 barriers per 2 j's. clds double-buffered across iterations.
template<int UF>
__global__ __launch_bounds__(1024, 4)
void caps_route4(const bf16* __restrict__ Xfrag, const bf16* __restrict__ Wfrag,
                 const float* __restrict__ Xf, const float* __restrict__ Wf,
                 const float* __restrict__ vsum, bf16* __restrict__ partial, int Jc)
{
    __shared__ float clds[2][2][16][33];

    const int tid  = threadIdx.x;
    const int w    = tid >> 6;
    const int lane = tid & 63;
    const int g    = lane >> 4;
    const int c0   = lane & 15;
    const int l5   = lane & 31;
    const bool lo  = lane < 32;
    int c, jr; decode_blk(blockIdx.x, UF, c, jr);

    const f32x4 ZV = {};
    const bf16x8 ZB = {};
    f32x4 sacc[4] = {ZV, ZV, ZV, ZV};

    const int j0 = jr * Jc;
    int jend = j0 + Jc; if (jend > JJ) jend = JJ;

    // hoisted vsum: vreg[r][t2] = vsum value for (b = c*16+g*4+r, k = w*2 + (t2>>1), o-half t2&1, o = c0 part)
    float vreg[4][4];
    {
        const float* vbase = vsum + ((size_t)(c * 16 + g * 4) * KC + w * 2) * DOO + c0;
#pragma unroll
        for (int r = 0; r < 4; ++r)
#pragma unroll
            for (int t2 = 0; t2 < 4; ++t2)
                vreg[r][t2] = vbase[(size_t)r * (KC * DOO) + (t2 >> 1) * 32 + (t2 & 1) * 16];
    }

    int itc = 0;
    for (int j = j0; j < jend; j += 2, ++itc) {
        const int pb = itc & 1;
        const int nj = (j + 1 < jend) ? 2 : 1;
        f32x4 hat[2][4];

        // ---- phase A: hat + logit partials for both j's ----
#pragma unroll
        for (int jj = 0; jj < 2; ++jj) {
            if (jj < nj) {
                const int ja = j + jj;
                bf16x8 afr = ZB;
                if (lo) {
                    if constexpr (UF) {
                        afr = *reinterpret_cast<const bf16x8*>(Xfrag + (((size_t)ja * 4 + c) * 32 + l5) * 8);
                    } else {
                        const float* s = Xf + ((size_t)(c * 16 + (l5 & 15)) * JJ + ja) * DI + (l5 >> 4) * 8;
#pragma unroll
                        for (int e = 0; e < 8; ++e) afr[e] = (bf16)s[e];
                    }
                }
                float lp[8] = {0.f, 0.f, 0.f, 0.f, 0.f, 0.f, 0.f, 0.f};
#pragma unroll
                for (int t2 = 0; t2 < 4; ++t2) {
                    bf16x8 bfr = ZB;
                    if (lo) {
                        if constexpr (UF) {
                            bfr = *reinterpret_cast<const bf16x8*>(
                                Wfrag + (((size_t)ja * 64 + w * 4 + t2) * 32 + l5) * 8);
                        } else {
                            int ko = (w * 4 + t2) * 16 + (l5 & 15);
                            const float* s = Wf + (size_t)ja * 16384 + (size_t)(ko >> 5) * 512
                                           + (size_t)((l5 >> 4) * 8) * 32 + (ko & 31);
#pragma unroll
                            for (int e = 0; e < 8; ++e) bfr[e] = (bf16)s[e * 32];
                        }
                    }
                    hat[jj][t2] = __builtin_amdgcn_mfma_f32_16x16x32_bf16(afr, bfr, ZV, 0, 0, 0);
#pragma unroll
                    for (int r = 0; r < 4; ++r)
                        lp[r * 2 + (t2 >> 1)] += hat[jj][t2][r] * vreg[r][t2];
                }
                // fold-butterfly over 16 o-lanes: lane c0<8 ends with total for (r=c0>>1, kk=c0&1)
                {
                    bool up1 = (c0 & 1) != 0;
#pragma unroll
                    for (int u = 0; u < 4; ++u) {
                        float sv = up1 ? lp[2 * u] : lp[2 * u + 1];
                        float kv = up1 ? lp[2 * u + 1] : lp[2 * u];
                        lp[u] = kv + __shfl_xor(sv, 1, 64);
                    }
                    bool up2 = (c0 & 2) != 0;
#pragma unroll
                    for (int u = 0; u < 2; ++u) {
                        float sv = up2 ? lp[2 * u] : lp[2 * u + 1];
                        float kv = up2 ? lp[2 * u + 1] : lp[2 * u];
                        lp[u] = kv + __shfl_xor(sv, 2, 64);
                    }
                    bool up4 = (c0 & 4) != 0;
                    {
                        float sv = up4 ? lp[0] : lp[1];
                        float kv = up4 ? lp[1] : lp[0];
                        lp[0] = kv + __shfl_xor(sv, 4, 64);
                    }
                    lp[0] += __shfl_xor(lp[0], 8, 64);
                    if (c0 < 8)
                        clds[pb][jj][g * 4 + (c0 >> 1)][w * 2 + (c0 & 1)] = lp[0];
                }
            }
        }
        __syncthreads();

        // ---- phase B: softmax over K=32; 32 rows (16 b x 2 j), one k per thread ----
        {
            int row = tid >> 5, k = tid & 31;
            int jj = row >> 4, bl = row & 15;
            float xv = clds[pb][jj][bl][k];
            float mx = xv;
#pragma unroll
            for (int m = 1; m < 32; m <<= 1) mx = fmaxf(mx, __shfl_xor(mx, m, 64));
            float ev = __expf(xv - mx);
            float sm = ev;
#pragma unroll
            for (int m = 1; m < 32; m <<= 1) sm += __shfl_xor(sm, m, 64);
            clds[pb][jj][bl][k] = ev / sm;
        }
        __syncthreads();

        // ---- phase C: weighted accumulate from held hat (pure VALU) ----
#pragma unroll
        for (int jj = 0; jj < 2; ++jj) {
            if (jj < nj) {
                float cw[4][2];
#pragma unroll
                for (int r = 0; r < 4; ++r)
#pragma unroll
                    for (int kk = 0; kk < 2; ++kk)
                        cw[r][kk] = clds[pb][jj][g * 4 + r][w * 2 + kk];
#pragma unroll
                for (int t2 = 0; t2 < 4; ++t2)
#pragma unroll
                    for (int r = 0; r < 4; ++r)
                        sacc[t2][r] += cw[r][t2 >> 1] * hat[jj][t2][r];
            }
        }
    }

    bf16* pout = partial + (size_t)jr * (BB * NKO);
#pragma unroll
    for (int t2 = 0; t2 < 4; ++t2) {
        bf16x4 o4;
#pragma unroll
        for (int r = 0; r < 4; ++r) o4[r] = (bf16)sacc[t2][r];
        *reinterpret_cast<bf16x4*>(pout + (((size_t)c * 64 + (w * 4 + t2)) * 64 + lane) * 4) = o4;
    }
}

// ---------------- reduce partials (natural order) + squash -> v ; update vsum ----------------
__global__ __launch_bounds__(256)
void caps_reduce3(const bf16* __restrict__ partial, float* __restrict__ vsum,
                  float* __restrict__ out, int P, int vmode, int wout)
{
    int gt   = blockIdx.x * 256 + threadIdx.x;   // < 8192
    int grp  = gt >> 6;                           // 0..127 = (c, k)
    int lane = gt & 63;
    int c = grp >> 5, k = grp & 31;
    int g = lane >> 4, c0 = lane & 15;

    const bf16* b0 = partial + ((size_t)(c * 64 + k * 2) * 64 + lane) * 4;
    float a0[4] = {0.f, 0.f, 0.f, 0.f}, a1[4] = {0.f, 0.f, 0.f, 0.f};
    for (int p = 0; p < P; ++p) {
        bf16x4 v0 = *reinterpret_cast<const bf16x4*>(b0 + (size_t)p * 65536);
        bf16x4 v1 = *reinterpret_cast<const bf16x4*>(b0 + 256 + (size_t)p * 65536);
#pragma unroll
        for (int r = 0; r < 4; ++r) { a0[r] += (float)v0[r]; a1[r] += (float)v1[r]; }
    }
#pragma unroll
    for (int r = 0; r < 4; ++r) {
        float s2 = a0[r] * a0[r] + a1[r] * a1[r];
#pragma unroll
        for (int m = 1; m < 16; m <<= 1) s2 += __shfl_xor(s2, m, 64);
        float scale = s2 / (1.0f + s2) / sqrtf(s2 + 1e-7f);
        int b  = c * 16 + g * 4 + r;
        int e0 = (b * KC + k) * DOO + c0;
        float v0o = scale * a0[r], v1o = scale * a1[r];
        if (vmode == 0)      { vsum[e0] = v0o;  vsum[e0 + 16] = v1o; }
        else if (vmode == 1) { vsum[e0] += v0o; vsum[e0 + 16] += v1o; }
        if (wout)            { out[e0] = v0o;   out[e0 + 16] = v1o; }
    }
}

extern "C" void kernel_launch(void* const* d_in, const int* in_sizes, int n_in,
                              void* d_out, int out_size, void* d_ws, size_t ws_size,
                              hipStream_t stream)
{
    const float* X  = (const float*)d_in[0];   // [64, 2048, 16] f32
    const float* Wg = (const float*)d_in[1];   // [2048, 32, 16, 32] f32
    float* out = (float*)d_out;                // [64, 32, 32] f32

    const size_t SLICE   = (size_t)BB * NKO;               // 65536 elements
    const size_t WFRAG_B = (size_t)JJ * 64 * 32 * 8 * 2;   // 67108864
    const size_t XFRAG_B = (size_t)JJ * 4 * 32 * 8 * 2;    // 4194304
    const size_t VS_B    = SLICE * sizeof(float);          // 262144

    int P = 128;
    int useFrag = 1;
    bf16 *Wfrag = nullptr, *Xfrag = nullptr, *partial = nullptr;
    float* vsum = nullptr;

    if (ws_size >= WFRAG_B + XFRAG_B + VS_B + (size_t)P * SLICE * 2) {
        Wfrag   = (bf16*)d_ws;
        Xfrag   = (bf16*)((char*)d_ws + WFRAG_B);
        vsum    = (float*)((char*)d_ws + WFRAG_B + XFRAG_B);
        partial = (bf16*)((char*)d_ws + WFRAG_B + XFRAG_B + VS_B);
    } else {
        useFrag = 0;
        size_t avail = (ws_size > VS_B) ? (ws_size - VS_B) / (SLICE * 2) : 1;
        P = (int)avail; if (P < 1) P = 1; if (P > 128) P = 128;
        vsum    = (float*)d_ws;
        partial = (bf16*)((char*)d_ws + VS_B);
    }
    const int Jc = (JJ + P - 1) / P;

    if (useFrag) {
        prep_w2<<<dim3(2048), dim3(256), 0, stream>>>(Wg, Wfrag);
        prep_x<<<dim3(1024),  dim3(256), 0, stream>>>(X,  Xfrag);
        caps_init<1><<<dim3(4 * P), dim3(1024), 0, stream>>>(Xfrag, Wfrag, X, Wg, partial, Jc);
        caps_reduce3<<<dim3(32), dim3(256), 0, stream>>>(partial, vsum, out, P, 0, 0);
        caps_route4<1><<<dim3(4 * P), dim3(1024), 0, stream>>>(Xfrag, Wfrag, X, Wg, vsum, partial, Jc);
        caps_reduce3<<<dim3(32), dim3(256), 0, stream>>>(partial, vsum, out, P, 1, 0);
        caps_route4<1><<<dim3(4 * P), dim3(1024), 0, stream>>>(Xfrag, Wfrag, X, Wg, vsum, partial, Jc);
        caps_reduce3<<<dim3(32), dim3(256), 0, stream>>>(partial, vsum, out, P, 2, 1);
    } else {
        caps_init<0><<<dim3(4 * P), dim3(1024), 0, stream>>>(Xfrag, Wfrag, X, Wg, partial, Jc);
        caps_reduce3<<<dim3(32), dim3(256), 0, stream>>>(partial, vsum, out, P, 0, 0);
        caps_route4<0><<<dim3(4 * P), dim3(1024), 0, stream>>>(Xfrag, Wfrag, X, Wg, vsum, partial, Jc);
        caps_reduce3<<<dim3(32), dim3(256), 0, stream>>>(partial, vsum, out, P, 1, 0);
        caps_route4<0><<<dim3(4 * P), dim3(1024), 0, stream>>>(Xfrag, Wfrag, X, Wg, vsum, partial, Jc);
        caps_reduce3<<<dim3(32), dim3(256), 0, stream>>>(partial, vsum, out, P, 2, 1);
    }
}